// Round 14
// baseline (211.325 us; speedup 1.0000x reference)
//
#include <hip/hip_runtime.h>
#include <math.h>

// CIN (xDeepFM) — split-bf16 16x16x32 MFMA, register-direct A, and
// ONE-BODY-DEFERRED Y-update: body f issues its 12 MFMAs into GA (or GB),
// then consumes the PREVIOUS body's G (complete long ago) into Y. The
// per-wave VALU no longer depends on in-flight MFMAs -> MFMA pipe and VALU
// overlap across phase-locked waves instead of serializing.
// y[b,o,d] = bias[o] + sum_f x[b,f,d] * ( sum_h W[o,f*H+h] * h_in[b,h,d] )
//   W*h ~= Whi*hhi + Whi*hlo + Wlo*hhi   (split bf16, lo*lo dropped)
// B=512, F=32, D=64, O=128; H0=32 (h=x), H1=H2=128; NPASS=H/32, NIT=NPASS*32.

typedef __attribute__((ext_vector_type(8))) short bf16x8;
typedef __attribute__((ext_vector_type(4))) float f32x4;
typedef __attribute__((ext_vector_type(4))) unsigned short u16x4;

#define HT_LO 4194304   // shorts: 512*64*128 (offset of lo plane)

__device__ __forceinline__ unsigned short f2bf(float f) {
  unsigned int u = __float_as_uint(f);
  u = (u + 0x7fffu + ((u >> 16) & 1u)) >> 16;   // RNE
  return (unsigned short)u;
}
__device__ __forceinline__ float bf2f(unsigned short h) {
  return __uint_as_float((unsigned int)h << 16);
}

__device__ __forceinline__ void gll16(const void* g, void* l) {
  __builtin_amdgcn_global_load_lds(
      (const __attribute__((address_space(1))) unsigned int*)g,
      (__attribute__((address_space(3))) unsigned int*)l, 16, 0, 0);
}

// ---- pre-pass: repack W (fp32, row-major 128xK) into split-bf16 image,
// chunk-sequential in iteration order: chunk c = pass*32 + f at 16B-unit c*1024.
// in-chunk (16B units): hi plane at [0,512) = mt*64+lane, lo plane at [512,1024).
// element: W[o = mt*16+(l&15)][kcol = f*H + pass*32 + (l>>4)*8 + j]
__global__ void repack_w_kernel(const float* __restrict__ W, unsigned short* __restrict__ dst,
                                int H, int nthreads)
{
  const int t = blockIdx.x * 256 + threadIdx.x;
  if (t >= nthreads) return;
  const int K = 32 * H;
  const int idx = t & 511;
  const int c   = t >> 9;
  const int pass = c >> 5, f = c & 31;
  const int mt = idx >> 6, l = idx & 63;
  const int o = mt * 16 + (l & 15);
  const int kcol = f * H + pass * 32 + ((l >> 4) & 3) * 8;
  const float* s = W + (size_t)o * K + kcol;
  u16x4 h0, h1, l0, l1;
#pragma unroll
  for (int j = 0; j < 4; ++j) {
    float v = s[j];
    unsigned short hb = f2bf(v);
    h0[j] = hb; l0[j] = f2bf(v - bf2f(hb));
    v = s[4 + j];
    hb = f2bf(v);
    h1[j] = hb; l1[j] = f2bf(v - bf2f(hb));
  }
  const size_t uhi = (size_t)c * 1024 + idx;         // 16B units
  const size_t ulo = (size_t)c * 1024 + 512 + idx;
  *(u16x4*)(dst + uhi * 8)     = h0;
  *(u16x4*)(dst + uhi * 8 + 4) = h1;
  *(u16x4*)(dst + ulo * 8)     = l0;
  *(u16x4*)(dst + ulo * 8 + 4) = l1;
}

// one body: read this body's scales into SC*, 12 MFMA (interleaved) into GC*,
// prefetch A for CNEXT into the consumed slot, then consume the PREVIOUS
// body's accumulators: Y += GP* x SP*  (GP complete long ago -> no stall).
#define BODY(FCUR, AHc, ALc, CNEXT, AHd, ALd, GC0, GC1, GC2, GC3,               \
             GP0, GP1, GP2, GP3, SC0, SC1, SC2, SC3, SP0, SP1, SP2, SP3)        \
  {                                                                             \
    SC0 = lx[(FCUR) * 64 +  0 + li];                                            \
    SC1 = lx[(FCUR) * 64 + 16 + li];                                            \
    SC2 = lx[(FCUR) * 64 + 32 + li];                                            \
    SC3 = lx[(FCUR) * 64 + 48 + li];                                            \
    __builtin_amdgcn_s_setprio(1);                                              \
    GC0 = __builtin_amdgcn_mfma_f32_16x16x32_bf16(AHc, Bh[0], zero4, 0, 0, 0);  \
    GC1 = __builtin_amdgcn_mfma_f32_16x16x32_bf16(AHc, Bh[1], zero4, 0, 0, 0);  \
    GC2 = __builtin_amdgcn_mfma_f32_16x16x32_bf16(AHc, Bh[2], zero4, 0, 0, 0);  \
    GC3 = __builtin_amdgcn_mfma_f32_16x16x32_bf16(AHc, Bh[3], zero4, 0, 0, 0);  \
    GC0 = __builtin_amdgcn_mfma_f32_16x16x32_bf16(AHc, Bl[0], GC0, 0, 0, 0);    \
    GC1 = __builtin_amdgcn_mfma_f32_16x16x32_bf16(AHc, Bl[1], GC1, 0, 0, 0);    \
    GC2 = __builtin_amdgcn_mfma_f32_16x16x32_bf16(AHc, Bl[2], GC2, 0, 0, 0);    \
    GC3 = __builtin_amdgcn_mfma_f32_16x16x32_bf16(AHc, Bl[3], GC3, 0, 0, 0);    \
    GC0 = __builtin_amdgcn_mfma_f32_16x16x32_bf16(ALc, Bh[0], GC0, 0, 0, 0);    \
    GC1 = __builtin_amdgcn_mfma_f32_16x16x32_bf16(ALc, Bh[1], GC1, 0, 0, 0);    \
    GC2 = __builtin_amdgcn_mfma_f32_16x16x32_bf16(ALc, Bh[2], GC2, 0, 0, 0);    \
    GC3 = __builtin_amdgcn_mfma_f32_16x16x32_bf16(ALc, Bh[3], GC3, 0, 0, 0);    \
    __builtin_amdgcn_s_setprio(0);                                              \
    {                                                                           \
      size_t cn_ = (size_t)(CNEXT);                                             \
      if (cn_ > (size_t)(NIT - 1)) cn_ = (size_t)(NIT - 1);                     \
      AHd = Abase[cn_ * 1024];                                                  \
      ALd = Abase[cn_ * 1024 + 512];                                            \
    }                                                                           \
    Y[0] += GP0 * SP0;                                                          \
    Y[1] += GP1 * SP1;                                                          \
    Y[2] += GP2 * SP2;                                                          \
    Y[3] += GP3 * SP3;                                                          \
  }

// ---- main layer kernel ----
// grid 512 x 512 threads; block = batch b; wave w owns o in [16w, 16w+16).
// LDS: 8KB raw x[b] only.
template<int H, int NPASS, bool FIRST, bool STORE_H>
__global__ __launch_bounds__(512, 4) void cin_mfma_layer(
    const unsigned short* __restrict__ Wimg,
    const float* __restrict__ x,               // (B,32,64) fp32
    const unsigned short* __restrict__ hTin,   // hi plane; lo at +HT_LO  (null if FIRST)
    const float* __restrict__ bias,
    unsigned short* __restrict__ hTout,        // hi plane; lo at +HT_LO
    float* __restrict__ outs, int col_off)
{
  constexpr int NIT = NPASS * 32;
  __shared__ char lds[8192];
  const int tid = threadIdx.x;
  const int w = tid >> 6, l = tid & 63, g = l >> 4, li = l & 15;
  const int b = blockIdx.x;
  const float* lx = (const float*)lds;

  // prologue: stage x[b] (8KB, one gll round, lane-linear), publish via barrier
  gll16(x + (size_t)b * 2048 + tid * 4, lds + w * 1024);

  f32x4 Y[4];
#pragma unroll
  for (int nt = 0; nt < 4; ++nt) Y[nt] = (f32x4){0.f, 0.f, 0.f, 0.f};
  const f32x4 zero4 = (f32x4){0.f, 0.f, 0.f, 0.f};
  bf16x8 Bh[4], Bl[4];

  asm volatile("s_waitcnt vmcnt(0)" ::: "memory");
  __builtin_amdgcn_s_barrier();   // the ONLY barrier

  if constexpr (FIRST) {
    // build split B-fragments from raw x in LDS (h == x; NPASS==1)
#pragma unroll
    for (int nt = 0; nt < 4; ++nt) {
      union { bf16x8 v; unsigned short u[8]; } th, tl;
#pragma unroll
      for (int j = 0; j < 8; ++j) {
        const float xv = lx[(g * 8 + j) * 64 + nt * 16 + li];
        const unsigned short hb = f2bf(xv);
        th.u[j] = hb; tl.u[j] = f2bf(xv - bf2f(hb));
      }
      Bh[nt] = th.v; Bl[nt] = tl.v;
    }
  }

  // wave's A-fragment base: 16B unit (w*64 + l); hi at c*1024, lo at +512
  const bf16x8* Abase = (const bf16x8*)Wimg + (w * 64 + l);

  // preload A(0) -> slot a, A(1) -> slot b
  bf16x8 AHa = Abase[0],    ALa = Abase[512];
  bf16x8 AHb = Abase[1024], ALb = Abase[1536];

  // ping-pong accumulator/scale sets; "B"-set starts as zero pending
  f32x4 GA0, GA1, GA2, GA3;
  f32x4 GB0 = zero4, GB1 = zero4, GB2 = zero4, GB3 = zero4;
  float sA0, sA1, sA2, sA3;
  float sB0 = 0.f, sB1 = 0.f, sB2 = 0.f, sB3 = 0.f;

  for (int pass = 0; pass < NPASS; ++pass) {
    if constexpr (!FIRST) {
      // B-fragments for this pass (h rows [pass*32, pass*32+32), reused over f)
#pragma unroll
      for (int nt = 0; nt < 4; ++nt) {
        const size_t off = (size_t)b * 8192 + (size_t)(nt * 16 + li) * 128
                         + pass * 32 + g * 8;
        Bh[nt] = *(const bf16x8*)(hTin + off);
        Bl[nt] = *(const bf16x8*)(hTin + HT_LO + off);
      }
    }
    const int cb = pass * 32;
#pragma unroll 1
    for (int fo = 0; fo < 32; fo += 2) {
      BODY(fo,     AHa, ALa, cb + fo + 2, AHa, ALa,
           GA0, GA1, GA2, GA3, GB0, GB1, GB2, GB3,
           sA0, sA1, sA2, sA3, sB0, sB1, sB2, sB3)
      BODY(fo + 1, AHb, ALb, cb + fo + 3, AHb, ALb,
           GB0, GB1, GB2, GB3, GA0, GA1, GA2, GA3,
           sB0, sB1, sB2, sB3, sA0, sA1, sA2, sA3)
    }
  }
  // consume the final pending accumulator (last body wrote the B-set)
  Y[0] += GB0 * sB0;
  Y[1] += GB1 * sB1;
  Y[2] += GB2 * sB2;
  Y[3] += GB3 * sB3;

  // ---- epilogue: bias, split-hT store, outs row-sums ----
  const f32x4 bv = *(const f32x4*)(bias + w * 16 + g * 4);
#pragma unroll
  for (int nt = 0; nt < 4; ++nt) Y[nt] += bv;

  if constexpr (STORE_H) {
#pragma unroll
    for (int nt = 0; nt < 4; ++nt) {
      const int d = nt * 16 + li;
      u16x4 ph, pl;
#pragma unroll
      for (int j = 0; j < 4; ++j) {
        const unsigned short hb = f2bf(Y[nt][j]);
        ph[j] = hb; pl[j] = f2bf(Y[nt][j] - bf2f(hb));
      }
      const size_t off = (size_t)b * 8192 + (size_t)d * 128 + w * 16 + g * 4;
      *(u16x4*)(hTout + off)         = ph;
      *(u16x4*)(hTout + HT_LO + off) = pl;
    }
  }

  {
    f32x4 s = Y[0] + Y[1] + Y[2] + Y[3];
#pragma unroll
    for (int m = 1; m < 16; m <<= 1) {
      s.x += __shfl_xor(s.x, m, 16);
      s.y += __shfl_xor(s.y, m, 16);
      s.z += __shfl_xor(s.z, m, 16);
      s.w += __shfl_xor(s.w, m, 16);
    }
    if (li == 0)
      *(f32x4*)(outs + (size_t)b * 384 + col_off + w * 16 + g * 4) = s;
  }
}

// ---- final: out[b] = sigmoid( relu(outs[b,:]) . Wout + bout ) ----
__global__ __launch_bounds__(64) void cin_final_kernel(
    const float* __restrict__ outs, const float* __restrict__ Wout,
    const float* __restrict__ bout, float* __restrict__ out)
{
  const int b = blockIdx.x;
  const int lane = threadIdx.x;
  float p = 0.f;
  for (int j = lane; j < 384; j += 64) {
    float v = outs[(size_t)b * 384 + j];
    v = v > 0.f ? v : 0.f;
    p = fmaf(v, Wout[j], p);
  }
#pragma unroll
  for (int m = 32; m; m >>= 1) p += __shfl_xor(p, m, 64);
  if (lane == 0) {
    const float t = p + bout[0];
    out[b] = 1.f / (1.f + expf(-t));
  }
}

extern "C" void kernel_launch(void* const* d_in, const int* in_sizes, int n_in,
                              void* d_out, int out_size, void* d_ws, size_t ws_size,
                              hipStream_t stream)
{
  const float* x    = (const float*)d_in[0];
  const float* W0   = (const float*)d_in[1];
  const float* b0   = (const float*)d_in[2];
  const float* W1   = (const float*)d_in[3];
  const float* b1   = (const float*)d_in[4];
  const float* W2   = (const float*)d_in[5];
  const float* b2   = (const float*)d_in[6];
  const float* Wout = (const float*)d_in[7];
  const float* bout = (const float*)d_in[8];
  float* out = (float*)d_out;

  char* ws = (char*)d_ws;
  unsigned short* hT1  = (unsigned short*)ws;                    // 16 MB (hi+lo)
  unsigned short* hT2  = (unsigned short*)(ws + (16 << 20));     // 16 MB
  float*          outs = (float*)        (ws + (32 << 20));      // 768 KB
  unsigned short* Wi0  = (unsigned short*)(ws + (33 << 20));               // 512 KB
  unsigned short* Wi1  = (unsigned short*)(ws + (33 << 20) + (1 << 19));   // 2 MB
  unsigned short* Wi2  = (unsigned short*)(ws + (33 << 20) + (1 << 19) + (2 << 20)); // 2 MB

  // nthreads = (K/32 chunks) * 512
  repack_w_kernel<<<64,  256, 0, stream>>>(W0, Wi0, 32,  16384);
  repack_w_kernel<<<256, 256, 0, stream>>>(W1, Wi1, 128, 65536);
  repack_w_kernel<<<256, 256, 0, stream>>>(W2, Wi2, 128, 65536);

  cin_mfma_layer<32,  1, true,  true ><<<512, 512, 0, stream>>>(Wi0, x, nullptr, b0, hT1, outs, 0);
  cin_mfma_layer<128, 4, false, true ><<<512, 512, 0, stream>>>(Wi1, x, hT1,    b1, hT2, outs, 128);
  cin_mfma_layer<128, 4, false, false><<<512, 512, 0, stream>>>(Wi2, x, hT2,    b2, nullptr, outs, 256);

  cin_final_kernel<<<512, 64, 0, stream>>>(outs, Wout, bout, out);
}

// Round 15
// 163.185 us; speedup vs baseline: 1.2950x; 1.2950x over previous
//
#include <hip/hip_runtime.h>
#include <math.h>

// CIN (xDeepFM) — fp16 MFMA, W single-plane / h split hi+lo (2 MFMA per product).
// y[b,o,d] = bias[o] + sum_f x[b,f,d] * ( sum_h W[o,f*H+h] * h_in[b,h,d] )
//   W*h ~= W16*hhi + W16*hlo ; W16 = fp16(W) (eps ~2^-12), hhi+hlo ~ h to 2^-22.
// Register-direct A (L2->VGPR, fragment-linear image), interleaved MFMA issue,
// wave-private everything -> no hot-loop barriers. LDS = 8KB x-tile only.
// B=512, F=32, D=64, O=128; H0=32 (h=x), H1=H2=128; NPASS=H/32, NIT=NPASS*32.

typedef __attribute__((ext_vector_type(8))) _Float16 f16x8;
typedef __attribute__((ext_vector_type(4))) float f32x4;
typedef __attribute__((ext_vector_type(4))) unsigned short u16x4;

#define HT_LO 4194304   // shorts: 512*64*128 (offset of lo plane)

__device__ __forceinline__ unsigned short f2h(float f) {
  union { _Float16 h; unsigned short u; } c; c.h = (_Float16)f; return c.u;
}
__device__ __forceinline__ float h2f(unsigned short u) {
  union { unsigned short u; _Float16 h; } c; c.u = u; return (float)c.h;
}

__device__ __forceinline__ void gll16(const void* g, void* l) {
  __builtin_amdgcn_global_load_lds(
      (const __attribute__((address_space(1))) unsigned int*)g,
      (__attribute__((address_space(3))) unsigned int*)l, 16, 0, 0);
}

// ---- pre-pass: repack W (fp32, row-major 128xK) into a SINGLE fp16 plane,
// chunk-sequential in iteration order: chunk c = pass*32 + f at 16B-unit c*512.
// unit t: idx = t&511 (mt=idx>>6, l=idx&63), c = t>>9.
// element: W[o = mt*16+(l&15)][kcol = f*H + pass*32 + ((l>>4)&3)*8 + j], j=0..7
__global__ void repack_w_kernel(const float* __restrict__ W, unsigned short* __restrict__ dst,
                                int H, int nthreads)
{
  const int t = blockIdx.x * 256 + threadIdx.x;
  if (t >= nthreads) return;
  const int K = 32 * H;
  const int idx = t & 511;
  const int c   = t >> 9;
  const int pass = c >> 5, f = c & 31;
  const int mt = idx >> 6, l = idx & 63;
  const int o = mt * 16 + (l & 15);
  const int kcol = f * H + pass * 32 + ((l >> 4) & 3) * 8;
  const float* s = W + (size_t)o * K + kcol;
  u16x4 a, bq;
#pragma unroll
  for (int j = 0; j < 4; ++j) {
    a[j]  = f2h(s[j]);
    bq[j] = f2h(s[4 + j]);
  }
  *(u16x4*)(dst + (size_t)t * 8)     = a;
  *(u16x4*)(dst + (size_t)t * 8 + 4) = bq;
}

// one body: scales (hoistable LDS reads), 8 MFMA interleaved (4 independent
// accumulators), prefetch A(CNEXT) into consumed slot, Y update.
#define BODY(FCUR, Ac, CNEXT, Ad)                                               \
  {                                                                             \
    const float sc0 = lx[(FCUR) * 64 +  0 + li];                                \
    const float sc1 = lx[(FCUR) * 64 + 16 + li];                                \
    const float sc2 = lx[(FCUR) * 64 + 32 + li];                                \
    const float sc3 = lx[(FCUR) * 64 + 48 + li];                                \
    f32x4 G0, G1, G2, G3;                                                       \
    __builtin_amdgcn_s_setprio(1);                                              \
    G0 = __builtin_amdgcn_mfma_f32_16x16x32_f16(Ac, Bh[0], zero4, 0, 0, 0);     \
    G1 = __builtin_amdgcn_mfma_f32_16x16x32_f16(Ac, Bh[1], zero4, 0, 0, 0);     \
    G2 = __builtin_amdgcn_mfma_f32_16x16x32_f16(Ac, Bh[2], zero4, 0, 0, 0);     \
    G3 = __builtin_amdgcn_mfma_f32_16x16x32_f16(Ac, Bh[3], zero4, 0, 0, 0);     \
    G0 = __builtin_amdgcn_mfma_f32_16x16x32_f16(Ac, Bl[0], G0, 0, 0, 0);        \
    G1 = __builtin_amdgcn_mfma_f32_16x16x32_f16(Ac, Bl[1], G1, 0, 0, 0);        \
    G2 = __builtin_amdgcn_mfma_f32_16x16x32_f16(Ac, Bl[2], G2, 0, 0, 0);        \
    G3 = __builtin_amdgcn_mfma_f32_16x16x32_f16(Ac, Bl[3], G3, 0, 0, 0);        \
    __builtin_amdgcn_s_setprio(0);                                              \
    {                                                                           \
      size_t cn_ = (size_t)(CNEXT);                                             \
      if (cn_ > (size_t)(NIT - 1)) cn_ = (size_t)(NIT - 1);                     \
      Ad = Abase[cn_ * 512];                                                    \
    }                                                                           \
    Y[0] += G0 * sc0;                                                           \
    Y[1] += G1 * sc1;                                                           \
    Y[2] += G2 * sc2;                                                           \
    Y[3] += G3 * sc3;                                                           \
  }

// ---- main layer kernel ----
// grid 512 x 512 threads; block = batch b; wave w owns o in [16w, 16w+16).
// LDS: 8KB raw x[b] only.
template<int H, int NPASS, bool FIRST, bool STORE_H>
__global__ __launch_bounds__(512, 4) void cin_mfma_layer(
    const unsigned short* __restrict__ Wimg,   // fp16 plane, fragment-linear
    const float* __restrict__ x,               // (B,32,64) fp32
    const unsigned short* __restrict__ hTin,   // fp16 hi plane; lo at +HT_LO (null if FIRST)
    const float* __restrict__ bias,
    unsigned short* __restrict__ hTout,        // fp16 hi plane; lo at +HT_LO
    float* __restrict__ outs, int col_off)
{
  constexpr int NIT = NPASS * 32;
  __shared__ char lds[8192];
  const int tid = threadIdx.x;
  const int w = tid >> 6, l = tid & 63, g = l >> 4, li = l & 15;
  const int b = blockIdx.x;
  const float* lx = (const float*)lds;

  // prologue: stage x[b] (8KB, one gll round, lane-linear), publish via barrier
  gll16(x + (size_t)b * 2048 + tid * 4, lds + w * 1024);

  f32x4 Y[4];
#pragma unroll
  for (int nt = 0; nt < 4; ++nt) Y[nt] = (f32x4){0.f, 0.f, 0.f, 0.f};
  const f32x4 zero4 = (f32x4){0.f, 0.f, 0.f, 0.f};
  f16x8 Bh[4], Bl[4];

  asm volatile("s_waitcnt vmcnt(0)" ::: "memory");
  __builtin_amdgcn_s_barrier();   // the ONLY barrier

  if constexpr (FIRST) {
    // build split B-fragments from raw x in LDS (h == x; NPASS==1)
#pragma unroll
    for (int nt = 0; nt < 4; ++nt) {
      union { f16x8 v; _Float16 u[8]; } th, tl;
#pragma unroll
      for (int j = 0; j < 8; ++j) {
        const float xv = lx[(g * 8 + j) * 64 + nt * 16 + li];
        const _Float16 hb = (_Float16)xv;
        th.u[j] = hb;
        tl.u[j] = (_Float16)(xv - (float)hb);
      }
      Bh[nt] = th.v; Bl[nt] = tl.v;
    }
  }

  // wave's A-fragment base: 16B unit (w*64 + l); chunk stride 512 units
  const f16x8* Abase = (const f16x8*)Wimg + (w * 64 + l);

  // preload A(0) -> slot a, A(1) -> slot b
  f16x8 Aa = Abase[0];
  f16x8 Ab = Abase[512];

  for (int pass = 0; pass < NPASS; ++pass) {
    if constexpr (!FIRST) {
      // B-fragments for this pass (h rows [pass*32, pass*32+32), reused over f)
#pragma unroll
      for (int nt = 0; nt < 4; ++nt) {
        const size_t off = (size_t)b * 8192 + (size_t)(nt * 16 + li) * 128
                         + pass * 32 + g * 8;
        Bh[nt] = *(const f16x8*)(hTin + off);
        Bl[nt] = *(const f16x8*)(hTin + HT_LO + off);
      }
    }
    const int cb = pass * 32;
#pragma unroll 1
    for (int fo = 0; fo < 32; fo += 2) {
      BODY(fo,     Aa, cb + fo + 2, Aa)
      BODY(fo + 1, Ab, cb + fo + 3, Ab)
    }
  }

  // ---- epilogue: bias, split-fp16 hT store, outs row-sums ----
  const f32x4 bv = *(const f32x4*)(bias + w * 16 + g * 4);
#pragma unroll
  for (int nt = 0; nt < 4; ++nt) Y[nt] += bv;

  if constexpr (STORE_H) {
#pragma unroll
    for (int nt = 0; nt < 4; ++nt) {
      const int d = nt * 16 + li;
      u16x4 ph, pl;
#pragma unroll
      for (int j = 0; j < 4; ++j) {
        const float v = Y[nt][j];
        const _Float16 hb = (_Float16)v;
        union { _Float16 h; unsigned short u; } ch, cl;
        ch.h = hb;
        cl.h = (_Float16)(v - (float)hb);
        ph[j] = ch.u; pl[j] = cl.u;
      }
      const size_t off = (size_t)b * 8192 + (size_t)d * 128 + w * 16 + g * 4;
      *(u16x4*)(hTout + off)         = ph;
      *(u16x4*)(hTout + HT_LO + off) = pl;
    }
  }

  {
    f32x4 s = Y[0] + Y[1] + Y[2] + Y[3];
#pragma unroll
    for (int m = 1; m < 16; m <<= 1) {
      s.x += __shfl_xor(s.x, m, 16);
      s.y += __shfl_xor(s.y, m, 16);
      s.z += __shfl_xor(s.z, m, 16);
      s.w += __shfl_xor(s.w, m, 16);
    }
    if (li == 0)
      *(f32x4*)(outs + (size_t)b * 384 + col_off + w * 16 + g * 4) = s;
  }
}

// ---- final: out[b] = sigmoid( relu(outs[b,:]) . Wout + bout ) ----
__global__ __launch_bounds__(64) void cin_final_kernel(
    const float* __restrict__ outs, const float* __restrict__ Wout,
    const float* __restrict__ bout, float* __restrict__ out)
{
  const int b = blockIdx.x;
  const int lane = threadIdx.x;
  float p = 0.f;
  for (int j = lane; j < 384; j += 64) {
    float v = outs[(size_t)b * 384 + j];
    v = v > 0.f ? v : 0.f;
    p = fmaf(v, Wout[j], p);
  }
#pragma unroll
  for (int m = 32; m; m >>= 1) p += __shfl_xor(p, m, 64);
  if (lane == 0) {
    const float t = p + bout[0];
    out[b] = 1.f / (1.f + expf(-t));
  }
}

extern "C" void kernel_launch(void* const* d_in, const int* in_sizes, int n_in,
                              void* d_out, int out_size, void* d_ws, size_t ws_size,
                              hipStream_t stream)
{
  const float* x    = (const float*)d_in[0];
  const float* W0   = (const float*)d_in[1];
  const float* b0   = (const float*)d_in[2];
  const float* W1   = (const float*)d_in[3];
  const float* b1   = (const float*)d_in[4];
  const float* W2   = (const float*)d_in[5];
  const float* b2   = (const float*)d_in[6];
  const float* Wout = (const float*)d_in[7];
  const float* bout = (const float*)d_in[8];
  float* out = (float*)d_out;

  char* ws = (char*)d_ws;
  unsigned short* hT1  = (unsigned short*)ws;                    // 16 MB (hi+lo fp16)
  unsigned short* hT2  = (unsigned short*)(ws + (16 << 20));     // 16 MB
  float*          outs = (float*)        (ws + (32 << 20));      // 768 KB
  unsigned short* Wi0  = (unsigned short*)(ws + (33 << 20));               // 256 KB
  unsigned short* Wi1  = (unsigned short*)(ws + (33 << 20) + (1 << 19));   // 1 MB
  unsigned short* Wi2  = (unsigned short*)(ws + (33 << 20) + (1 << 19) + (2 << 20)); // 1 MB

  // nthreads = (K/32 chunks) * 512
  repack_w_kernel<<<64,  256, 0, stream>>>(W0, Wi0, 32,  16384);
  repack_w_kernel<<<256, 256, 0, stream>>>(W1, Wi1, 128, 65536);
  repack_w_kernel<<<256, 256, 0, stream>>>(W2, Wi2, 128, 65536);

  cin_mfma_layer<32,  1, true,  true ><<<512, 512, 0, stream>>>(Wi0, x, nullptr, b0, hT1, outs, 0);
  cin_mfma_layer<128, 4, false, true ><<<512, 512, 0, stream>>>(Wi1, x, hT1,    b1, hT2, outs, 128);
  cin_mfma_layer<128, 4, false, false><<<512, 512, 0, stream>>>(Wi2, x, hT2,    b2, nullptr, outs, 256);

  cin_final_kernel<<<512, 64, 0, stream>>>(outs, Wout, bout, out);
}

// Round 16
// 114.940 us; speedup vs baseline: 1.8386x; 1.4197x over previous
//
#include <hip/hip_runtime.h>
#include <math.h>

// CIN (xDeepFM) — fp16 MFMA, W and h both single-plane fp16 (1 logical product
// = 1 MFMA pair-term less: 4 MFMA/body).
// y[b,o,d] = bias[o] + sum_f x[b,f,d] * ( sum_h W[o,f*H+h] * h_in[b,h,d] )
//   W*h ~= W16*h16 ; eps_W ~ eps_h ~ 2^-12 (fp16 RNE), x-scale stays fp32.
// Register-direct A (L2->VGPR, fragment-linear image), interleaved MFMA issue,
// wave-private everything -> no hot-loop barriers. LDS = 8KB x-tile only.
// B=512, F=32, D=64, O=128; H0=32 (h=x), H1=H2=128; NPASS=H/32, NIT=NPASS*32.

typedef __attribute__((ext_vector_type(8))) _Float16 f16x8;
typedef __attribute__((ext_vector_type(4))) float f32x4;
typedef __attribute__((ext_vector_type(4))) unsigned short u16x4;

__device__ __forceinline__ unsigned short f2h(float f) {
  union { _Float16 h; unsigned short u; } c; c.h = (_Float16)f; return c.u;
}

__device__ __forceinline__ void gll16(const void* g, void* l) {
  __builtin_amdgcn_global_load_lds(
      (const __attribute__((address_space(1))) unsigned int*)g,
      (__attribute__((address_space(3))) unsigned int*)l, 16, 0, 0);
}

// ---- pre-pass: repack W (fp32, row-major 128xK) into a SINGLE fp16 plane,
// chunk-sequential in iteration order: chunk c = pass*32 + f at 16B-unit c*512.
// unit t: idx = t&511 (mt=idx>>6, l=idx&63), c = t>>9.
// element: W[o = mt*16+(l&15)][kcol = f*H + pass*32 + ((l>>4)&3)*8 + j], j=0..7
__global__ void repack_w_kernel(const float* __restrict__ W, unsigned short* __restrict__ dst,
                                int H, int nthreads)
{
  const int t = blockIdx.x * 256 + threadIdx.x;
  if (t >= nthreads) return;
  const int K = 32 * H;
  const int idx = t & 511;
  const int c   = t >> 9;
  const int pass = c >> 5, f = c & 31;
  const int mt = idx >> 6, l = idx & 63;
  const int o = mt * 16 + (l & 15);
  const int kcol = f * H + pass * 32 + ((l >> 4) & 3) * 8;
  const float* s = W + (size_t)o * K + kcol;
  u16x4 a, bq;
#pragma unroll
  for (int j = 0; j < 4; ++j) {
    a[j]  = f2h(s[j]);
    bq[j] = f2h(s[4 + j]);
  }
  *(u16x4*)(dst + (size_t)t * 8)     = a;
  *(u16x4*)(dst + (size_t)t * 8 + 4) = bq;
}

// one body: scales (hoistable LDS reads), 4 independent MFMAs, prefetch
// A(CNEXT) into consumed slot, Y update in fp32.
#define BODY(FCUR, Ac, CNEXT, Ad)                                               \
  {                                                                             \
    const float sc0 = lx[(FCUR) * 64 +  0 + li];                                \
    const float sc1 = lx[(FCUR) * 64 + 16 + li];                                \
    const float sc2 = lx[(FCUR) * 64 + 32 + li];                                \
    const float sc3 = lx[(FCUR) * 64 + 48 + li];                                \
    f32x4 G0, G1, G2, G3;                                                       \
    __builtin_amdgcn_s_setprio(1);                                              \
    G0 = __builtin_amdgcn_mfma_f32_16x16x32_f16(Ac, Bh[0], zero4, 0, 0, 0);     \
    G1 = __builtin_amdgcn_mfma_f32_16x16x32_f16(Ac, Bh[1], zero4, 0, 0, 0);     \
    G2 = __builtin_amdgcn_mfma_f32_16x16x32_f16(Ac, Bh[2], zero4, 0, 0, 0);     \
    G3 = __builtin_amdgcn_mfma_f32_16x16x32_f16(Ac, Bh[3], zero4, 0, 0, 0);     \
    __builtin_amdgcn_s_setprio(0);                                              \
    {                                                                           \
      size_t cn_ = (size_t)(CNEXT);                                             \
      if (cn_ > (size_t)(NIT - 1)) cn_ = (size_t)(NIT - 1);                     \
      Ad = Abase[cn_ * 512];                                                    \
    }                                                                           \
    Y[0] += G0 * sc0;                                                           \
    Y[1] += G1 * sc1;                                                           \
    Y[2] += G2 * sc2;                                                           \
    Y[3] += G3 * sc3;                                                           \
  }

// ---- main layer kernel ----
// grid 512 x 512 threads; block = batch b; wave w owns o in [16w, 16w+16).
// LDS: 8KB raw x[b] only.
template<int H, int NPASS, bool FIRST, bool STORE_H>
__global__ __launch_bounds__(512, 4) void cin_mfma_layer(
    const unsigned short* __restrict__ Wimg,   // fp16 plane, fragment-linear
    const float* __restrict__ x,               // (B,32,64) fp32
    const unsigned short* __restrict__ hTin,   // fp16 hT[b][d][hrow] (null if FIRST)
    const float* __restrict__ bias,
    unsigned short* __restrict__ hTout,        // fp16 hT[b][d][orow]
    float* __restrict__ outs, int col_off)
{
  constexpr int NIT = NPASS * 32;
  __shared__ char lds[8192];
  const int tid = threadIdx.x;
  const int w = tid >> 6, l = tid & 63, g = l >> 4, li = l & 15;
  const int b = blockIdx.x;
  const float* lx = (const float*)lds;

  // prologue: stage x[b] (8KB, one gll round, lane-linear), publish via barrier
  gll16(x + (size_t)b * 2048 + tid * 4, lds + w * 1024);

  f32x4 Y[4];
#pragma unroll
  for (int nt = 0; nt < 4; ++nt) Y[nt] = (f32x4){0.f, 0.f, 0.f, 0.f};
  const f32x4 zero4 = (f32x4){0.f, 0.f, 0.f, 0.f};
  f16x8 Bh[4];

  asm volatile("s_waitcnt vmcnt(0)" ::: "memory");
  __builtin_amdgcn_s_barrier();   // the ONLY barrier

  if constexpr (FIRST) {
    // build fp16 B-fragments from raw x in LDS (h == x; NPASS==1)
#pragma unroll
    for (int nt = 0; nt < 4; ++nt) {
      union { f16x8 v; _Float16 u[8]; } th;
#pragma unroll
      for (int j = 0; j < 8; ++j) {
        const float xv = lx[(g * 8 + j) * 64 + nt * 16 + li];
        th.u[j] = (_Float16)xv;
      }
      Bh[nt] = th.v;
    }
  }

  // wave's A-fragment base: 16B unit (w*64 + l); chunk stride 512 units
  const f16x8* Abase = (const f16x8*)Wimg + (w * 64 + l);

  // preload A(0) -> slot a, A(1) -> slot b
  f16x8 Aa = Abase[0];
  f16x8 Ab = Abase[512];

  for (int pass = 0; pass < NPASS; ++pass) {
    if constexpr (!FIRST) {
      // B-fragments for this pass (h rows [pass*32, pass*32+32), reused over f)
#pragma unroll
      for (int nt = 0; nt < 4; ++nt) {
        const size_t off = (size_t)b * 8192 + (size_t)(nt * 16 + li) * 128
                         + pass * 32 + g * 8;
        Bh[nt] = *(const f16x8*)(hTin + off);
      }
    }
    const int cb = pass * 32;
#pragma unroll 1
    for (int fo = 0; fo < 32; fo += 2) {
      BODY(fo,     Aa, cb + fo + 2, Aa)
      BODY(fo + 1, Ab, cb + fo + 3, Ab)
    }
  }

  // ---- epilogue: bias, fp16 hT store, outs row-sums ----
  const f32x4 bv = *(const f32x4*)(bias + w * 16 + g * 4);
#pragma unroll
  for (int nt = 0; nt < 4; ++nt) Y[nt] += bv;

  if constexpr (STORE_H) {
#pragma unroll
    for (int nt = 0; nt < 4; ++nt) {
      const int d = nt * 16 + li;
      u16x4 ph;
#pragma unroll
      for (int j = 0; j < 4; ++j) ph[j] = f2h(Y[nt][j]);
      const size_t off = (size_t)b * 8192 + (size_t)d * 128 + w * 16 + g * 4;
      *(u16x4*)(hTout + off) = ph;
    }
  }

  {
    f32x4 s = Y[0] + Y[1] + Y[2] + Y[3];
#pragma unroll
    for (int m = 1; m < 16; m <<= 1) {
      s.x += __shfl_xor(s.x, m, 16);
      s.y += __shfl_xor(s.y, m, 16);
      s.z += __shfl_xor(s.z, m, 16);
      s.w += __shfl_xor(s.w, m, 16);
    }
    if (li == 0)
      *(f32x4*)(outs + (size_t)b * 384 + col_off + w * 16 + g * 4) = s;
  }
}

// ---- final: out[b] = sigmoid( relu(outs[b,:]) . Wout + bout ) ----
__global__ __launch_bounds__(64) void cin_final_kernel(
    const float* __restrict__ outs, const float* __restrict__ Wout,
    const float* __restrict__ bout, float* __restrict__ out)
{
  const int b = blockIdx.x;
  const int lane = threadIdx.x;
  float p = 0.f;
  for (int j = lane; j < 384; j += 64) {
    float v = outs[(size_t)b * 384 + j];
    v = v > 0.f ? v : 0.f;
    p = fmaf(v, Wout[j], p);
  }
#pragma unroll
  for (int m = 32; m; m >>= 1) p += __shfl_xor(p, m, 64);
  if (lane == 0) {
    const float t = p + bout[0];
    out[b] = 1.f / (1.f + expf(-t));
  }
}

extern "C" void kernel_launch(void* const* d_in, const int* in_sizes, int n_in,
                              void* d_out, int out_size, void* d_ws, size_t ws_size,
                              hipStream_t stream)
{
  const float* x    = (const float*)d_in[0];
  const float* W0   = (const float*)d_in[1];
  const float* b0   = (const float*)d_in[2];
  const float* W1   = (const float*)d_in[3];
  const float* b1   = (const float*)d_in[4];
  const float* W2   = (const float*)d_in[5];
  const float* b2   = (const float*)d_in[6];
  const float* Wout = (const float*)d_in[7];
  const float* bout = (const float*)d_in[8];
  float* out = (float*)d_out;

  char* ws = (char*)d_ws;
  unsigned short* hT1  = (unsigned short*)ws;                    // 8 MB (fp16)
  unsigned short* hT2  = (unsigned short*)(ws + (8 << 20));      // 8 MB
  float*          outs = (float*)        (ws + (16 << 20));      // 768 KB
  unsigned short* Wi0  = (unsigned short*)(ws + (17 << 20));               // 256 KB
  unsigned short* Wi1  = (unsigned short*)(ws + (17 << 20) + (1 << 19));   // 1 MB
  unsigned short* Wi2  = (unsigned short*)(ws + (17 << 20) + (1 << 19) + (1 << 20)); // 1 MB

  // nthreads = (K/32 chunks) * 512
  repack_w_kernel<<<64,  256, 0, stream>>>(W0, Wi0, 32,  16384);
  repack_w_kernel<<<256, 256, 0, stream>>>(W1, Wi1, 128, 65536);
  repack_w_kernel<<<256, 256, 0, stream>>>(W2, Wi2, 128, 65536);

  cin_mfma_layer<32,  1, true,  true ><<<512, 512, 0, stream>>>(Wi0, x, nullptr, b0, hT1, outs, 0);
  cin_mfma_layer<128, 4, false, true ><<<512, 512, 0, stream>>>(Wi1, x, hT1,    b1, hT2, outs, 128);
  cin_mfma_layer<128, 4, false, false><<<512, 512, 0, stream>>>(Wi2, x, hT2,    b2, nullptr, outs, 256);

  cin_final_kernel<<<512, 64, 0, stream>>>(outs, Wout, bout, out);
}

// Round 17
// 106.485 us; speedup vs baseline: 1.9845x; 1.0794x over previous
//
#include <hip/hip_runtime.h>
#include <math.h>

// CIN (xDeepFM) — fp16 MFMA (W,h single-plane), register-direct A with
// pointer-bump prefetch, fused final epilogue. 4 dispatches total.
// y[b,o,d] = bias[o] + sum_f x[b,f,d] * ( sum_h W[o,f*H+h] * h_in[b,h,d] )
// out[b] = sigmoid( relu(concat outs) . Wout + bout )  (fused into layer 3)
// B=512, F=32, D=64, O=128; H0=32 (h=x), H1=H2=128; NPASS=H/32, NIT=NPASS*32.

typedef __attribute__((ext_vector_type(8))) _Float16 f16x8;
typedef __attribute__((ext_vector_type(4))) float f32x4;
typedef __attribute__((ext_vector_type(4))) unsigned short u16x4;

__device__ __forceinline__ unsigned short f2h(float f) {
  union { _Float16 h; unsigned short u; } c; c.h = (_Float16)f; return c.u;
}

__device__ __forceinline__ void gll16(const void* g, void* l) {
  __builtin_amdgcn_global_load_lds(
      (const __attribute__((address_space(1))) unsigned int*)g,
      (__attribute__((address_space(3))) unsigned int*)l, 16, 0, 0);
}

// ---- single merged pre-pass: repack all three W into fp16 fragment-linear
// images, chunk-sequential in iteration order (chunk c = pass*32+f at unit c*512).
// blocks [0,64) -> W0 (16384 units), [64,320) -> W1, [320,576) -> W2.
// element: W[o = mt*16+(l&15)][kcol = f*H + pass*32 + ((l>>4)&3)*8 + j], j=0..7
__global__ void repack_w_all(const float* __restrict__ W0q, const float* __restrict__ W1q,
                             const float* __restrict__ W2q,
                             unsigned short* __restrict__ D0, unsigned short* __restrict__ D1,
                             unsigned short* __restrict__ D2)
{
  const int blk = blockIdx.x;
  const float* W; unsigned short* dst; int H, t;
  if (blk < 64)       { W = W0q; dst = D0; H = 32;  t = blk * 256 + threadIdx.x; }
  else if (blk < 320) { W = W1q; dst = D1; H = 128; t = (blk - 64) * 256 + threadIdx.x; }
  else                { W = W2q; dst = D2; H = 128; t = (blk - 320) * 256 + threadIdx.x; }
  const int K = 32 * H;
  const int idx = t & 511;
  const int c   = t >> 9;
  const int pass = c >> 5, f = c & 31;
  const int mt = idx >> 6, l = idx & 63;
  const int o = mt * 16 + (l & 15);
  const int kcol = f * H + pass * 32 + ((l >> 4) & 3) * 8;
  const float* s = W + (size_t)o * K + kcol;
  u16x4 a, bq;
#pragma unroll
  for (int j = 0; j < 4; ++j) {
    a[j]  = f2h(s[j]);
    bq[j] = f2h(s[4 + j]);
  }
  *(u16x4*)(dst + (size_t)t * 8)     = a;
  *(u16x4*)(dst + (size_t)t * 8 + 4) = bq;
}

// one body: scales via bumped pointer, 4 independent MFMAs, pointer-bump
// prefetch of A two chunks ahead (image padded +2 chunks), Y update fp32.
#define BODY(SPOFF, Ac, Ad, Ap)                                                 \
  {                                                                             \
    const float sc0 = lxp[(SPOFF) +  0 + li];                                   \
    const float sc1 = lxp[(SPOFF) + 16 + li];                                   \
    const float sc2 = lxp[(SPOFF) + 32 + li];                                   \
    const float sc3 = lxp[(SPOFF) + 48 + li];                                   \
    f32x4 G0, G1, G2, G3;                                                       \
    __builtin_amdgcn_s_setprio(1);                                              \
    G0 = __builtin_amdgcn_mfma_f32_16x16x32_f16(Ac, Bh[0], zero4, 0, 0, 0);     \
    G1 = __builtin_amdgcn_mfma_f32_16x16x32_f16(Ac, Bh[1], zero4, 0, 0, 0);     \
    G2 = __builtin_amdgcn_mfma_f32_16x16x32_f16(Ac, Bh[2], zero4, 0, 0, 0);     \
    G3 = __builtin_amdgcn_mfma_f32_16x16x32_f16(Ac, Bh[3], zero4, 0, 0, 0);     \
    __builtin_amdgcn_s_setprio(0);                                              \
    Ad = Ap[0];                                                                 \
    Ap += 1024;                                                                 \
    Y[0] += G0 * sc0;                                                           \
    Y[1] += G1 * sc1;                                                           \
    Y[2] += G2 * sc2;                                                           \
    Y[3] += G3 * sc3;                                                           \
  }

// ---- main layer kernel ----
// grid 512 x 512 threads; block = batch b; wave w owns o in [16w, 16w+16).
// LDS: 8KB raw x[b] (reused as 128-float exchange buffer in the FINAL epilogue).
template<int H, int NPASS, bool FIRST, bool STORE_H, bool FINAL>
__global__ __launch_bounds__(512, 4) void cin_mfma_layer(
    const unsigned short* __restrict__ Wimg,   // fp16 plane, fragment-linear (+2 chunk pad)
    const float* __restrict__ x,               // (B,32,64) fp32
    const unsigned short* __restrict__ hTin,   // fp16 hT[b][d][hrow] (null if FIRST)
    const float* __restrict__ bias,
    unsigned short* __restrict__ hTout,        // fp16 hT[b][d][orow]
    float* __restrict__ outs, int col_off,     // (B,256) cols 0..255 (layers 0,1)
    const float* __restrict__ Wout,            // (384) — FINAL only
    const float* __restrict__ bout,            // (1)   — FINAL only
    float* __restrict__ out)                   // (B)   — FINAL only
{
  __shared__ char lds[8192];
  const int tid = threadIdx.x;
  const int w = tid >> 6, l = tid & 63, g = l >> 4, li = l & 15;
  const int b = blockIdx.x;
  const float* lx = (const float*)lds;

  // prologue: stage x[b] (8KB, one gll round, lane-linear), publish via barrier
  gll16(x + (size_t)b * 2048 + tid * 4, lds + w * 1024);

  f32x4 Y[4];
#pragma unroll
  for (int nt = 0; nt < 4; ++nt) Y[nt] = (f32x4){0.f, 0.f, 0.f, 0.f};
  const f32x4 zero4 = (f32x4){0.f, 0.f, 0.f, 0.f};
  f16x8 Bh[4];

  asm volatile("s_waitcnt vmcnt(0)" ::: "memory");
  __builtin_amdgcn_s_barrier();

  if constexpr (FIRST) {
    // build fp16 B-fragments from raw x in LDS (h == x; NPASS==1)
#pragma unroll
    for (int nt = 0; nt < 4; ++nt) {
      union { f16x8 v; _Float16 u[8]; } th;
#pragma unroll
      for (int j = 0; j < 8; ++j) {
        const float xv = lx[(g * 8 + j) * 64 + nt * 16 + li];
        th.u[j] = (_Float16)xv;
      }
      Bh[nt] = th.v;
    }
  }

  // wave's A-fragment base: 16B unit (w*64 + l); chunk stride 512 units
  const f16x8* Abase = (const f16x8*)Wimg + (w * 64 + l);

  // preload A(0)/A(1); prefetch pointers start at chunks 2 (even) and 3 (odd)
  f16x8 Aa = Abase[0];
  f16x8 Ab = Abase[512];
  const f16x8* ApA = Abase + 1024;
  const f16x8* ApB = Abase + 1536;

  for (int pass = 0; pass < NPASS; ++pass) {
    if constexpr (!FIRST) {
      // B-fragments for this pass (h rows [pass*32, pass*32+32), reused over f)
#pragma unroll
      for (int nt = 0; nt < 4; ++nt) {
        const size_t off = (size_t)b * 8192 + (size_t)(nt * 16 + li) * 128
                         + pass * 32 + g * 8;
        Bh[nt] = *(const f16x8*)(hTin + off);
      }
    }
    const float* lxp = lx;
#pragma unroll 1
    for (int fo = 0; fo < 32; fo += 2) {
      BODY(0,  Aa, Aa, ApA)
      BODY(64, Ab, Ab, ApB)
      lxp += 128;
    }
  }

  // ---- epilogue: bias, fp16 hT store, row-sums ----
  const f32x4 bv = *(const f32x4*)(bias + w * 16 + g * 4);
#pragma unroll
  for (int nt = 0; nt < 4; ++nt) Y[nt] += bv;

  if constexpr (STORE_H) {
#pragma unroll
    for (int nt = 0; nt < 4; ++nt) {
      const int d = nt * 16 + li;
      u16x4 ph;
#pragma unroll
      for (int j = 0; j < 4; ++j) ph[j] = f2h(Y[nt][j]);
      const size_t off = (size_t)b * 8192 + (size_t)d * 128 + w * 16 + g * 4;
      *(u16x4*)(hTout + off) = ph;
    }
  }

  f32x4 s = Y[0] + Y[1] + Y[2] + Y[3];
#pragma unroll
  for (int m = 1; m < 16; m <<= 1) {
    s.x += __shfl_xor(s.x, m, 16);
    s.y += __shfl_xor(s.y, m, 16);
    s.z += __shfl_xor(s.z, m, 16);
    s.w += __shfl_xor(s.w, m, 16);
  }

  if constexpr (FINAL) {
    // fused: out[b] = sigmoid( relu(outs[b,0:256]).Wout[0:256]
    //                        + relu(own 128 sums).Wout[256:384] + bout )
    __builtin_amdgcn_s_barrier();            // all waves done reading lx
    float* shs = (float*)lds;
    if (li == 0) *(f32x4*)(shs + w * 16 + g * 4) = s;   // own col-sums 256+..
    __builtin_amdgcn_s_barrier();
    if (w == 0) {
      float acc;
      {
        float v0 = shs[l];      v0 = v0 > 0.f ? v0 : 0.f;
        float v1 = shs[l + 64]; v1 = v1 > 0.f ? v1 : 0.f;
        acc = v0 * Wout[256 + l] + v1 * Wout[320 + l];
      }
#pragma unroll
      for (int q = 0; q < 4; ++q) {
        float v = outs[(size_t)b * 256 + q * 64 + l];
        v = v > 0.f ? v : 0.f;
        acc = fmaf(v, Wout[q * 64 + l], acc);
      }
#pragma unroll
      for (int m = 32; m; m >>= 1) acc += __shfl_xor(acc, m, 64);
      if (l == 0) {
        const float t = acc + bout[0];
        out[b] = 1.f / (1.f + expf(-t));
      }
    }
  } else {
    if (li == 0)
      *(f32x4*)(outs + (size_t)b * 256 + col_off + w * 16 + g * 4) = s;
  }
}

extern "C" void kernel_launch(void* const* d_in, const int* in_sizes, int n_in,
                              void* d_out, int out_size, void* d_ws, size_t ws_size,
                              hipStream_t stream)
{
  const float* x    = (const float*)d_in[0];
  const float* W0   = (const float*)d_in[1];
  const float* b0   = (const float*)d_in[2];
  const float* W1   = (const float*)d_in[3];
  const float* b1   = (const float*)d_in[4];
  const float* W2   = (const float*)d_in[5];
  const float* b2   = (const float*)d_in[6];
  const float* Wout = (const float*)d_in[7];
  const float* bout = (const float*)d_in[8];
  float* out = (float*)d_out;

  char* ws = (char*)d_ws;
  unsigned short* hT1  = (unsigned short*)ws;                        // 8 MB (fp16)
  unsigned short* hT2  = (unsigned short*)(ws + (8 << 20));          // 8 MB
  float*          outs = (float*)        (ws + (16 << 20));          // 512 KB
  unsigned short* Wi0  = (unsigned short*)(ws + (17 << 20));                 // 256 KB + pad
  unsigned short* Wi1  = (unsigned short*)(ws + (17 << 20) + (1 << 19));     // 1 MB + pad
  unsigned short* Wi2  = (unsigned short*)(ws + (19 << 20));                 // 1 MB + pad

  repack_w_all<<<576, 256, 0, stream>>>(W0, W1, W2, Wi0, Wi1, Wi2);

  cin_mfma_layer<32,  1, true,  true,  false><<<512, 512, 0, stream>>>(
      Wi0, x, nullptr, b0, hT1, outs, 0, nullptr, nullptr, nullptr);
  cin_mfma_layer<128, 4, false, true,  false><<<512, 512, 0, stream>>>(
      Wi1, x, hT1, b1, hT2, outs, 128, nullptr, nullptr, nullptr);
  cin_mfma_layer<128, 4, false, false, true ><<<512, 512, 0, stream>>>(
      Wi2, x, hT2, b2, nullptr, outs, 0, Wout, bout, out);
}

// Round 18
// 105.037 us; speedup vs baseline: 2.0119x; 1.0138x over previous
//
#include <hip/hip_runtime.h>
#include <math.h>

// CIN (xDeepFM) — fp16 MFMA (W,h single-plane), register-direct A with
// pointer-bump prefetch, fused final epilogue, NO setprio, b128 scale reads.
// y[b,o,d] = bias[o] + sum_f x[b,f,d] * ( sum_h W[o,f*H+h] * h_in[b,h,d] )
// out[b] = sigmoid( relu(concat outs) . Wout + bout )  (fused into layer 3)
// B=512, F=32, D=64, O=128; H0=32 (h=x), H1=H2=128; NPASS=H/32.

typedef __attribute__((ext_vector_type(8))) _Float16 f16x8;
typedef __attribute__((ext_vector_type(4))) float f32x4;
typedef __attribute__((ext_vector_type(4))) unsigned short u16x4;

__device__ __forceinline__ unsigned short f2h(float f) {
  union { _Float16 h; unsigned short u; } c; c.h = (_Float16)f; return c.u;
}

__device__ __forceinline__ void gll16(const void* g, void* l) {
  __builtin_amdgcn_global_load_lds(
      (const __attribute__((address_space(1))) unsigned int*)g,
      (__attribute__((address_space(3))) unsigned int*)l, 16, 0, 0);
}

// ---- single merged pre-pass: repack all three W into fp16 fragment-linear
// images, chunk-sequential in iteration order (chunk c = pass*32+f at unit c*512).
// blocks [0,64) -> W0, [64,320) -> W1, [320,576) -> W2.
// element: W[o = mt*16+(l&15)][kcol = f*H + pass*32 + ((l>>4)&3)*8 + j], j=0..7
__global__ void repack_w_all(const float* __restrict__ W0q, const float* __restrict__ W1q,
                             const float* __restrict__ W2q,
                             unsigned short* __restrict__ D0, unsigned short* __restrict__ D1,
                             unsigned short* __restrict__ D2)
{
  const int blk = blockIdx.x;
  const float* W; unsigned short* dst; int H, t;
  if (blk < 64)       { W = W0q; dst = D0; H = 32;  t = blk * 256 + threadIdx.x; }
  else if (blk < 320) { W = W1q; dst = D1; H = 128; t = (blk - 64) * 256 + threadIdx.x; }
  else                { W = W2q; dst = D2; H = 128; t = (blk - 320) * 256 + threadIdx.x; }
  const int K = 32 * H;
  const int idx = t & 511;
  const int c   = t >> 9;
  const int pass = c >> 5, f = c & 31;
  const int mt = idx >> 6, l = idx & 63;
  const int o = mt * 16 + (l & 15);
  const int kcol = f * H + pass * 32 + ((l >> 4) & 3) * 8;
  const float* s = W + (size_t)o * K + kcol;
  u16x4 a, bq;
#pragma unroll
  for (int j = 0; j < 4; ++j) {
    a[j]  = f2h(s[j]);
    bq[j] = f2h(s[4 + j]);
  }
  *(u16x4*)(dst + (size_t)t * 8)     = a;
  *(u16x4*)(dst + (size_t)t * 8 + 4) = bq;
}

// one body: ONE b128 scale read, 4 independent MFMAs, pointer-bump prefetch
// of A two chunks ahead (image padded +2 chunks), Y update fp32.
#define BODY(SPOFF, Ac, Ad, Ap)                                                 \
  {                                                                             \
    const f32x4 scv = *(const f32x4*)(lxp + (SPOFF));                           \
    f32x4 G0, G1, G2, G3;                                                       \
    G0 = __builtin_amdgcn_mfma_f32_16x16x32_f16(Ac, Bh[0], zero4, 0, 0, 0);     \
    G1 = __builtin_amdgcn_mfma_f32_16x16x32_f16(Ac, Bh[1], zero4, 0, 0, 0);     \
    G2 = __builtin_amdgcn_mfma_f32_16x16x32_f16(Ac, Bh[2], zero4, 0, 0, 0);     \
    G3 = __builtin_amdgcn_mfma_f32_16x16x32_f16(Ac, Bh[3], zero4, 0, 0, 0);     \
    Ad = Ap[0];                                                                 \
    Ap += 1024;                                                                 \
    Y[0] += G0 * scv[0];                                                        \
    Y[1] += G1 * scv[1];                                                        \
    Y[2] += G2 * scv[2];                                                        \
    Y[3] += G3 * scv[3];                                                        \
  }

// ---- main layer kernel ----
// grid 512 x 512 threads; block = batch b; wave w owns o in [16w, 16w+16).
// LDS: [0,8KB) raw x[b]; [8KB,16KB) xt transposed scales xt[f][li][q]=x[f][q*16+li].
template<int H, int NPASS, bool FIRST, bool STORE_H, bool FINAL>
__global__ __launch_bounds__(512, 4) void cin_mfma_layer(
    const unsigned short* __restrict__ Wimg,   // fp16 plane, fragment-linear (+2 chunk pad)
    const float* __restrict__ x,               // (B,32,64) fp32
    const unsigned short* __restrict__ hTin,   // fp16 hT[b][d][hrow] (null if FIRST)
    const float* __restrict__ bias,
    unsigned short* __restrict__ hTout,        // fp16 hT[b][d][orow]
    float* __restrict__ outs, int col_off,     // (B,256) cols 0..255 (layers 0,1)
    const float* __restrict__ Wout,            // (384) — FINAL only
    const float* __restrict__ bout,            // (1)   — FINAL only
    float* __restrict__ out)                   // (B)   — FINAL only
{
  __shared__ char lds[16384];
  const int tid = threadIdx.x;
  const int w = tid >> 6, l = tid & 63, g = l >> 4, li = l & 15;
  const int b = blockIdx.x;
  const float* lx  = (const float*)lds;
  const float* lxt = (const float*)(lds + 8192);

  // prologue: stage x[b] (8KB, one gll round, lane-linear)
  gll16(x + (size_t)b * 2048 + tid * 4, lds + w * 1024);

  f32x4 Y[4];
#pragma unroll
  for (int nt = 0; nt < 4; ++nt) Y[nt] = (f32x4){0.f, 0.f, 0.f, 0.f};
  const f32x4 zero4 = (f32x4){0.f, 0.f, 0.f, 0.f};
  f16x8 Bh[4];

  asm volatile("s_waitcnt vmcnt(0)" ::: "memory");
  __builtin_amdgcn_s_barrier();

  // build transposed scale tile: xt[tf][tl][q] = x[tf][q*16+tl]  (512 thr = 32x16)
  {
    const int tf = tid >> 4, tl = tid & 15;
    f32x4 vv;
    vv[0] = lx[tf * 64 +  0 + tl];
    vv[1] = lx[tf * 64 + 16 + tl];
    vv[2] = lx[tf * 64 + 32 + tl];
    vv[3] = lx[tf * 64 + 48 + tl];
    *(f32x4*)(lds + 8192 + (tf * 16 + tl) * 16) = vv;
  }
  __builtin_amdgcn_s_barrier();

  if constexpr (FIRST) {
    // build fp16 B-fragments from raw x in LDS (h == x; NPASS==1)
#pragma unroll
    for (int nt = 0; nt < 4; ++nt) {
      union { f16x8 v; _Float16 u[8]; } th;
#pragma unroll
      for (int j = 0; j < 8; ++j) {
        const float xv = lx[(g * 8 + j) * 64 + nt * 16 + li];
        th.u[j] = (_Float16)xv;
      }
      Bh[nt] = th.v;
    }
  }

  // wave's A-fragment base: 16B unit (w*64 + l); chunk stride 512 units
  const f16x8* Abase = (const f16x8*)Wimg + (w * 64 + l);

  // preload A(0)/A(1); prefetch pointers start at chunks 2 (even) and 3 (odd)
  f16x8 Aa = Abase[0];
  f16x8 Ab = Abase[512];
  const f16x8* ApA = Abase + 1024;
  const f16x8* ApB = Abase + 1536;

  for (int pass = 0; pass < NPASS; ++pass) {
    if constexpr (!FIRST) {
      // B-fragments for this pass (h rows [pass*32, pass*32+32), reused over f)
#pragma unroll
      for (int nt = 0; nt < 4; ++nt) {
        const size_t off = (size_t)b * 8192 + (size_t)(nt * 16 + li) * 128
                         + pass * 32 + g * 8;
        Bh[nt] = *(const f16x8*)(hTin + off);
      }
    }
    const float* lxp = lxt + li * 4;
#pragma unroll 1
    for (int fo = 0; fo < 32; fo += 2) {
      BODY(0,   Aa, Aa, ApA)
      BODY(64,  Ab, Ab, ApB)
      lxp += 128;
    }
  }

  // ---- epilogue: bias, fp16 hT store, row-sums ----
  const f32x4 bv = *(const f32x4*)(bias + w * 16 + g * 4);
#pragma unroll
  for (int nt = 0; nt < 4; ++nt) Y[nt] += bv;

  if constexpr (STORE_H) {
#pragma unroll
    for (int nt = 0; nt < 4; ++nt) {
      const int d = nt * 16 + li;
      u16x4 ph;
#pragma unroll
      for (int j = 0; j < 4; ++j) ph[j] = f2h(Y[nt][j]);
      const size_t off = (size_t)b * 8192 + (size_t)d * 128 + w * 16 + g * 4;
      *(u16x4*)(hTout + off) = ph;
    }
  }

  f32x4 s = Y[0] + Y[1] + Y[2] + Y[3];
#pragma unroll
  for (int m = 1; m < 16; m <<= 1) {
    s.x += __shfl_xor(s.x, m, 16);
    s.y += __shfl_xor(s.y, m, 16);
    s.z += __shfl_xor(s.z, m, 16);
    s.w += __shfl_xor(s.w, m, 16);
  }

  if constexpr (FINAL) {
    // fused: out[b] = sigmoid( relu(outs[b,0:256]).Wout[0:256]
    //                        + relu(own 128 sums).Wout[256:384] + bout )
    __builtin_amdgcn_s_barrier();            // all waves done reading lx/lxt
    float* shs = (float*)lds;
    if (li == 0) *(f32x4*)(shs + w * 16 + g * 4) = s;   // own col-sums 256+..
    __builtin_amdgcn_s_barrier();
    if (w == 0) {
      float acc;
      {
        float v0 = shs[l];      v0 = v0 > 0.f ? v0 : 0.f;
        float v1 = shs[l + 64]; v1 = v1 > 0.f ? v1 : 0.f;
        acc = v0 * Wout[256 + l] + v1 * Wout[320 + l];
      }
#pragma unroll
      for (int q = 0; q < 4; ++q) {
        float v = outs[(size_t)b * 256 + q * 64 + l];
        v = v > 0.f ? v : 0.f;
        acc = fmaf(v, Wout[q * 64 + l], acc);
      }
#pragma unroll
      for (int m = 32; m; m >>= 1) acc += __shfl_xor(acc, m, 64);
      if (l == 0) {
        const float t = acc + bout[0];
        out[b] = 1.f / (1.f + expf(-t));
      }
    }
  } else {
    if (li == 0)
      *(f32x4*)(outs + (size_t)b * 256 + col_off + w * 16 + g * 4) = s;
  }
}

extern "C" void kernel_launch(void* const* d_in, const int* in_sizes, int n_in,
                              void* d_out, int out_size, void* d_ws, size_t ws_size,
                              hipStream_t stream)
{
  const float* x    = (const float*)d_in[0];
  const float* W0   = (const float*)d_in[1];
  const float* b0   = (const float*)d_in[2];
  const float* W1   = (const float*)d_in[3];
  const float* b1   = (const float*)d_in[4];
  const float* W2   = (const float*)d_in[5];
  const float* b2   = (const float*)d_in[6];
  const float* Wout = (const float*)d_in[7];
  const float* bout = (const float*)d_in[8];
  float* out = (float*)d_out;

  char* ws = (char*)d_ws;
  unsigned short* hT1  = (unsigned short*)ws;                        // 8 MB (fp16)
  unsigned short* hT2  = (unsigned short*)(ws + (8 << 20));          // 8 MB
  float*          outs = (float*)        (ws + (16 << 20));          // 512 KB
  unsigned short* Wi0  = (unsigned short*)(ws + (17 << 20));                 // 256 KB + pad
  unsigned short* Wi1  = (unsigned short*)(ws + (17 << 20) + (1 << 19));     // 1 MB + pad
  unsigned short* Wi2  = (unsigned short*)(ws + (19 << 20));                 // 1 MB + pad

  repack_w_all<<<576, 256, 0, stream>>>(W0, W1, W2, Wi0, Wi1, Wi2);

  cin_mfma_layer<32,  1, true,  true,  false><<<512, 512, 0, stream>>>(
      Wi0, x, nullptr, b0, hT1, outs, 0, nullptr, nullptr, nullptr);
  cin_mfma_layer<128, 4, false, true,  false><<<512, 512, 0, stream>>>(
      Wi1, x, hT1, b1, hT2, outs, 128, nullptr, nullptr, nullptr);
  cin_mfma_layer<128, 4, false, false, true ><<<512, 512, 0, stream>>>(
      Wi2, x, hT2, b2, nullptr, outs, 0, Wout, bout, out);
}

// Round 19
// 101.662 us; speedup vs baseline: 2.0787x; 1.0332x over previous
//
#include <hip/hip_runtime.h>
#include <math.h>

// CIN (xDeepFM) — fp16 MFMA (W,h single-plane), 2 BATCHES PER BLOCK (A-loads,
// scale reads, loop control amortized over 2x MFMA), register-direct A with
// pointer-bump prefetch, fused final epilogue. 4 dispatches total.
// y[b,o,d] = bias[o] + sum_f x[b,f,d] * ( sum_h W[o,f*H+h] * h_in[b,h,d] )
// out[b] = sigmoid( relu(concat outs) . Wout + bout )  (fused into layer 3)
// B=512, F=32, D=64, O=128; H0=32 (h=x), H1=H2=128; NPASS=H/32.

typedef __attribute__((ext_vector_type(8))) _Float16 f16x8;
typedef __attribute__((ext_vector_type(4))) float f32x4;
typedef __attribute__((ext_vector_type(4))) unsigned short u16x4;

__device__ __forceinline__ unsigned short f2h(float f) {
  union { _Float16 h; unsigned short u; } c; c.h = (_Float16)f; return c.u;
}

__device__ __forceinline__ void gll16(const void* g, void* l) {
  __builtin_amdgcn_global_load_lds(
      (const __attribute__((address_space(1))) unsigned int*)g,
      (__attribute__((address_space(3))) unsigned int*)l, 16, 0, 0);
}

// ---- single merged pre-pass: repack all three W into fp16 fragment-linear
// images, chunk-sequential in iteration order (chunk c = pass*32+f at unit c*512).
// blocks [0,64) -> W0, [64,320) -> W1, [320,576) -> W2.
// element: W[o = mt*16+(l&15)][kcol = f*H + pass*32 + ((l>>4)&3)*8 + j], j=0..7
__global__ void repack_w_all(const float* __restrict__ W0q, const float* __restrict__ W1q,
                             const float* __restrict__ W2q,
                             unsigned short* __restrict__ D0, unsigned short* __restrict__ D1,
                             unsigned short* __restrict__ D2)
{
  const int blk = blockIdx.x;
  const float* W; unsigned short* dst; int H, t;
  if (blk < 64)       { W = W0q; dst = D0; H = 32;  t = blk * 256 + threadIdx.x; }
  else if (blk < 320) { W = W1q; dst = D1; H = 128; t = (blk - 64) * 256 + threadIdx.x; }
  else                { W = W2q; dst = D2; H = 128; t = (blk - 320) * 256 + threadIdx.x; }
  const int K = 32 * H;
  const int idx = t & 511;
  const int c   = t >> 9;
  const int pass = c >> 5, f = c & 31;
  const int mt = idx >> 6, l = idx & 63;
  const int o = mt * 16 + (l & 15);
  const int kcol = f * H + pass * 32 + ((l >> 4) & 3) * 8;
  const float* s = W + (size_t)o * K + kcol;
  u16x4 a, bq;
#pragma unroll
  for (int j = 0; j < 4; ++j) {
    a[j]  = f2h(s[j]);
    bq[j] = f2h(s[4 + j]);
  }
  *(u16x4*)(dst + (size_t)t * 8)     = a;
  *(u16x4*)(dst + (size_t)t * 8 + 4) = bq;
}

// one body: 2 b128 scale reads, 8 MFMAs (4 per batch, batch-interleaved),
// ONE pointer-bump A prefetch (shared by both batches), 32 fmacs.
#define BODY(SPOFF, Ac, Ad, Ap)                                                 \
  {                                                                             \
    const f32x4 sv0 = *(const f32x4*)(lxp0 + (SPOFF));                          \
    const f32x4 sv1 = *(const f32x4*)(lxp1 + (SPOFF));                          \
    f32x4 G00, G01, G02, G03, G10, G11, G12, G13;                               \
    G00 = __builtin_amdgcn_mfma_f32_16x16x32_f16(Ac, Bh0[0], zero4, 0, 0, 0);   \
    G10 = __builtin_amdgcn_mfma_f32_16x16x32_f16(Ac, Bh1[0], zero4, 0, 0, 0);   \
    G01 = __builtin_amdgcn_mfma_f32_16x16x32_f16(Ac, Bh0[1], zero4, 0, 0, 0);   \
    G11 = __builtin_amdgcn_mfma_f32_16x16x32_f16(Ac, Bh1[1], zero4, 0, 0, 0);   \
    G02 = __builtin_amdgcn_mfma_f32_16x16x32_f16(Ac, Bh0[2], zero4, 0, 0, 0);   \
    G12 = __builtin_amdgcn_mfma_f32_16x16x32_f16(Ac, Bh1[2], zero4, 0, 0, 0);   \
    G03 = __builtin_amdgcn_mfma_f32_16x16x32_f16(Ac, Bh0[3], zero4, 0, 0, 0);   \
    G13 = __builtin_amdgcn_mfma_f32_16x16x32_f16(Ac, Bh1[3], zero4, 0, 0, 0);   \
    Ad = Ap[0];                                                                 \
    Ap += 1024;                                                                 \
    Y0[0] += G00 * sv0[0];  Y0[1] += G01 * sv0[1];                              \
    Y0[2] += G02 * sv0[2];  Y0[3] += G03 * sv0[3];                              \
    Y1[0] += G10 * sv1[0];  Y1[1] += G11 * sv1[1];                              \
    Y1[2] += G12 * sv1[2];  Y1[3] += G13 * sv1[3];                              \
  }

// ---- main layer kernel ----
// grid 256 x 512 threads; block handles b0=2*blk, b0+1; wave w owns o in [16w,16w+16).
// LDS: [0,8K) x[b0]; [8K,16K) x[b0+1]; [16K,24K) xt0; [24K,32K) xt1
//      xt[f][li][q] = x[f][q*16+li] (per-body scales as one b128 read each).
template<int H, int NPASS, bool FIRST, bool STORE_H, bool FINAL>
__global__ __launch_bounds__(512, 2) void cin_mfma_layer(
    const unsigned short* __restrict__ Wimg,   // fp16 plane, fragment-linear (+2 chunk pad)
    const float* __restrict__ x,               // (B,32,64) fp32
    const unsigned short* __restrict__ hTin,   // fp16 hT[b][d][hrow] (null if FIRST)
    const float* __restrict__ bias,
    unsigned short* __restrict__ hTout,        // fp16 hT[b][d][orow]
    float* __restrict__ outs, int col_off,     // (B,256) cols 0..255 (layers 0,1)
    const float* __restrict__ Wout,            // (384) — FINAL only
    const float* __restrict__ bout,            // (1)   — FINAL only
    float* __restrict__ out)                   // (B)   — FINAL only
{
  __shared__ char lds[32768];
  const int tid = threadIdx.x;
  const int w = tid >> 6, l = tid & 63, g = l >> 4, li = l & 15;
  const int b0 = blockIdx.x * 2;
  const float* lx0 = (const float*)lds;
  const float* lx1 = (const float*)(lds + 8192);
  const float* xt0 = (const float*)(lds + 16384);
  const float* xt1 = (const float*)(lds + 24576);

  // prologue: stage x[b0], x[b0+1] (2 x 8KB, lane-linear)
  gll16(x + (size_t)b0 * 2048 + tid * 4,       lds + w * 1024);
  gll16(x + (size_t)(b0 + 1) * 2048 + tid * 4, lds + 8192 + w * 1024);

  f32x4 Y0[4], Y1[4];
#pragma unroll
  for (int nt = 0; nt < 4; ++nt) {
    Y0[nt] = (f32x4){0.f, 0.f, 0.f, 0.f};
    Y1[nt] = (f32x4){0.f, 0.f, 0.f, 0.f};
  }
  const f32x4 zero4 = (f32x4){0.f, 0.f, 0.f, 0.f};
  f16x8 Bh0[4], Bh1[4];

  asm volatile("s_waitcnt vmcnt(0)" ::: "memory");
  __builtin_amdgcn_s_barrier();

  // build transposed scale tiles for both batches (512 thr = 32f x 16li)
  {
    const int tf = tid >> 4, tl = tid & 15;
    f32x4 v0, v1;
    v0[0] = lx0[tf * 64 +  0 + tl]; v0[1] = lx0[tf * 64 + 16 + tl];
    v0[2] = lx0[tf * 64 + 32 + tl]; v0[3] = lx0[tf * 64 + 48 + tl];
    v1[0] = lx1[tf * 64 +  0 + tl]; v1[1] = lx1[tf * 64 + 16 + tl];
    v1[2] = lx1[tf * 64 + 32 + tl]; v1[3] = lx1[tf * 64 + 48 + tl];
    *(f32x4*)(lds + 16384 + (tf * 16 + tl) * 16) = v0;
    *(f32x4*)(lds + 24576 + (tf * 16 + tl) * 16) = v1;
  }
  __builtin_amdgcn_s_barrier();

  if constexpr (FIRST) {
    // build fp16 B-fragments from raw x (h == x; NPASS==1), both batches
#pragma unroll
    for (int nt = 0; nt < 4; ++nt) {
      union { f16x8 v; _Float16 u[8]; } t0, t1;
#pragma unroll
      for (int j = 0; j < 8; ++j) {
        t0.u[j] = (_Float16)lx0[(g * 8 + j) * 64 + nt * 16 + li];
        t1.u[j] = (_Float16)lx1[(g * 8 + j) * 64 + nt * 16 + li];
      }
      Bh0[nt] = t0.v; Bh1[nt] = t1.v;
    }
  }

  // wave's A-fragment base: 16B unit (w*64 + l); chunk stride 512 units
  const f16x8* Abase = (const f16x8*)Wimg + (w * 64 + l);
  f16x8 Aa = Abase[0];
  f16x8 Ab = Abase[512];
  const f16x8* ApA = Abase + 1024;
  const f16x8* ApB = Abase + 1536;

  for (int pass = 0; pass < NPASS; ++pass) {
    if constexpr (!FIRST) {
      // B-fragments for this pass, both batches (reused across all 32 f)
#pragma unroll
      for (int nt = 0; nt < 4; ++nt) {
        const size_t co = (size_t)(nt * 16 + li) * 128 + pass * 32 + g * 8;
        Bh0[nt] = *(const f16x8*)(hTin + (size_t)b0 * 8192 + co);
        Bh1[nt] = *(const f16x8*)(hTin + (size_t)(b0 + 1) * 8192 + co);
      }
    }
    const float* lxp0 = xt0 + li * 4;
    const float* lxp1 = xt1 + li * 4;
#pragma unroll 1
    for (int fo = 0; fo < 32; fo += 2) {
      BODY(0,  Aa, Aa, ApA)
      BODY(64, Ab, Ab, ApB)
      lxp0 += 128;
      lxp1 += 128;
    }
  }

  // ---- epilogue: bias, fp16 hT stores, row-sums (both batches) ----
  const f32x4 bv = *(const f32x4*)(bias + w * 16 + g * 4);
#pragma unroll
  for (int nt = 0; nt < 4; ++nt) { Y0[nt] += bv; Y1[nt] += bv; }

  if constexpr (STORE_H) {
#pragma unroll
    for (int nt = 0; nt < 4; ++nt) {
      const int d = nt * 16 + li;
      u16x4 p0, p1;
#pragma unroll
      for (int j = 0; j < 4; ++j) { p0[j] = f2h(Y0[nt][j]); p1[j] = f2h(Y1[nt][j]); }
      const size_t co = (size_t)d * 128 + w * 16 + g * 4;
      *(u16x4*)(hTout + (size_t)b0 * 8192 + co)       = p0;
      *(u16x4*)(hTout + (size_t)(b0 + 1) * 8192 + co) = p1;
    }
  }

  f32x4 s0 = Y0[0] + Y0[1] + Y0[2] + Y0[3];
  f32x4 s1 = Y1[0] + Y1[1] + Y1[2] + Y1[3];
#pragma unroll
  for (int m = 1; m < 16; m <<= 1) {
    s0.x += __shfl_xor(s0.x, m, 16); s0.y += __shfl_xor(s0.y, m, 16);
    s0.z += __shfl_xor(s0.z, m, 16); s0.w += __shfl_xor(s0.w, m, 16);
    s1.x += __shfl_xor(s1.x, m, 16); s1.y += __shfl_xor(s1.y, m, 16);
    s1.z += __shfl_xor(s1.z, m, 16); s1.w += __shfl_xor(s1.w, m, 16);
  }

  if constexpr (FINAL) {
    // fused: out[b] = sigmoid( relu(outs[b,0:256]).Wout[0:256]
    //                        + relu(own 128 sums).Wout[256:384] + bout ), both b
    __builtin_amdgcn_s_barrier();            // all waves done reading lx/xt
    float* shs = (float*)lds;
    if (li == 0) {
      *(f32x4*)(shs + w * 16 + g * 4)       = s0;
      *(f32x4*)(shs + 128 + w * 16 + g * 4) = s1;
    }
    __builtin_amdgcn_s_barrier();
    if (w < 2) {
      const int bb = b0 + w;
      const float* sh = shs + w * 128;
      float acc;
      {
        float v0 = sh[l];      v0 = v0 > 0.f ? v0 : 0.f;
        float v1 = sh[l + 64]; v1 = v1 > 0.f ? v1 : 0.f;
        acc = v0 * Wout[256 + l] + v1 * Wout[320 + l];
      }
#pragma unroll
      for (int q = 0; q < 4; ++q) {
        float v = outs[(size_t)bb * 256 + q * 64 + l];
        v = v > 0.f ? v : 0.f;
        acc = fmaf(v, Wout[q * 64 + l], acc);
      }
#pragma unroll
      for (int m = 32; m; m >>= 1) acc += __shfl_xor(acc, m, 64);
      if (l == 0) {
        const float t = acc + bout[0];
        out[bb] = 1.f / (1.f + expf(-t));
      }
    }
  } else {
    if (li == 0) {
      *(f32x4*)(outs + (size_t)b0 * 256 + col_off + w * 16 + g * 4)       = s0;
      *(f32x4*)(outs + (size_t)(b0 + 1) * 256 + col_off + w * 16 + g * 4) = s1;
    }
  }
}

extern "C" void kernel_launch(void* const* d_in, const int* in_sizes, int n_in,
                              void* d_out, int out_size, void* d_ws, size_t ws_size,
                              hipStream_t stream)
{
  const float* x    = (const float*)d_in[0];
  const float* W0   = (const float*)d_in[1];
  const float* b0   = (const float*)d_in[2];
  const float* W1   = (const float*)d_in[3];
  const float* b1   = (const float*)d_in[4];
  const float* W2   = (const float*)d_in[5];
  const float* b2   = (const float*)d_in[6];
  const float* Wout = (const float*)d_in[7];
  const float* bout = (const float*)d_in[8];
  float* out = (float*)d_out;

  char* ws = (char*)d_ws;
  unsigned short* hT1  = (unsigned short*)ws;                        // 8 MB (fp16)
  unsigned short* hT2  = (unsigned short*)(ws + (8 << 20));          // 8 MB
  float*          outs = (float*)        (ws + (16 << 20));          // 512 KB
  unsigned short* Wi0  = (unsigned short*)(ws + (17 << 20));                 // 256 KB + pad
  unsigned short* Wi1  = (unsigned short*)(ws + (17 << 20) + (1 << 19));     // 1 MB + pad
  unsigned short* Wi2  = (unsigned short*)(ws + (19 << 20));                 // 1 MB + pad

  repack_w_all<<<576, 256, 0, stream>>>(W0, W1, W2, Wi0, Wi1, Wi2);

  cin_mfma_layer<32,  1, true,  true,  false><<<256, 512, 0, stream>>>(
      Wi0, x, nullptr, b0, hT1, outs, 0, nullptr, nullptr, nullptr);
  cin_mfma_layer<128, 4, false, true,  false><<<256, 512, 0, stream>>>(
      Wi1, x, hT1, b1, hT2, outs, 128, nullptr, nullptr, nullptr);
  cin_mfma_layer<128, 4, false, false, true ><<<256, 512, 0, stream>>>(
      Wi2, x, hT2, b2, nullptr, outs, 0, Wout, bout, out);
}